// Round 1
// baseline (317.822 us; speedup 1.0000x reference)
//
#include <hip/hip_runtime.h>

// out[b, d] = sum_{i : seg[i]==b} table[ids[i], d] * ratings[i]
// seg sorted -> contiguous runs. Two kernels:
//  1) seg_offsets: scatter run boundaries into offsets[BATCH+1] (in d_ws)
//  2) embed_bag:   TWO waves per segment (interleaved quad ownership) for
//                  32 waves/CU occupancy; explicit id-prefetch rotation to
//                  keep table gathers in flight; LDS combine (deterministic).

#define TOTAL 409600
#define BATCH 4096
#define DIM   64

__global__ __launch_bounds__(256) void seg_offsets_kernel(
    const int* __restrict__ seg, int* __restrict__ offsets)
{
    int i = blockIdx.x * blockDim.x + threadIdx.x;
    if (i >= TOTAL) return;
    int cur  = seg[i];
    int prev = (i == 0) ? -1 : seg[i - 1];
    for (int b = prev + 1; b <= cur; ++b) offsets[b] = i;   // lower_bound(seg, b)
    if (i == TOTAL - 1) {
        for (int b = cur + 1; b <= BATCH; ++b) offsets[b] = TOTAL;
    }
}

// Block = 256 threads = 4 waves = 2 segments x 2 waves.
// Wave layout per segment: half h (0/1) owns quads q = h, h+2, h+4, ...
// (quad = 4 consecutive rows; 4 lane-groups of 16 lanes each load one row).
__global__ __launch_bounds__(256, 8) void embed_bag_kernel(
    const int*   __restrict__ ids,
    const float* __restrict__ ratings,
    const int*   __restrict__ offsets,
    const float* __restrict__ table,
    float*       __restrict__ out)
{
    __shared__ float4 part[2][16];

    const int wid        = threadIdx.x >> 6;   // 0..3
    const int lane       = threadIdx.x & 63;
    const int seg_in_blk = wid >> 1;           // 0..1
    const int half       = wid & 1;            // 0..1
    const int b          = blockIdx.x * 2 + seg_in_blk;
    const int grp        = lane >> 4;          // which of 4 rows in a quad
    const int col        = lane & 15;          // which float4 of the 64-dim row

    const int start = offsets[b];
    const int end   = offsets[b + 1];
    const int n     = end - start;

    float4 acc = make_float4(0.f, 0.f, 0.f, 0.f);

    constexpr int U = 4;   // quads per iteration per wave (16 rows/wave/iter)

    // iteration i handles quads q = half + 2*(U*i + u), u in [0,U)
    // max row touched by iter i: start + 4*half + 32*i + 27  (must be <= n-1)
    const int t     = n - 28 - 4 * half;
    const int iFull = (t >= 0) ? ((t >> 5) + 1) : 0;

    int   idc[U];
    float rtc[U];
    if (iFull > 0) {
        #pragma unroll
        for (int u = 0; u < U; ++u) {
            int r = start + 4 * (half + 2 * u) + grp;
            idc[u] = ids[r];
            rtc[u] = ratings[r];
        }
    }

    for (int i = 0; i < iFull; ++i) {
        // issue all U table gathers for the current group
        float4 v0 = ((const float4*)(table + (size_t)idc[0] * DIM))[col];
        float4 v1 = ((const float4*)(table + (size_t)idc[1] * DIM))[col];
        float4 v2 = ((const float4*)(table + (size_t)idc[2] * DIM))[col];
        float4 v3 = ((const float4*)(table + (size_t)idc[3] * DIM))[col];

        // prefetch next group's ids/ratings while gathers are in flight
        int   idn[U] = {0, 0, 0, 0};
        float rtn[U] = {0.f, 0.f, 0.f, 0.f};
        if (i + 1 < iFull) {                    // wave-uniform branch
            #pragma unroll
            for (int u = 0; u < U; ++u) {
                int r = start + 4 * (half + 2 * (U * (i + 1) + u)) + grp;
                idn[u] = ids[r];
                rtn[u] = ratings[r];
            }
        }

        acc.x = fmaf(v0.x, rtc[0], acc.x);
        acc.y = fmaf(v0.y, rtc[0], acc.y);
        acc.z = fmaf(v0.z, rtc[0], acc.z);
        acc.w = fmaf(v0.w, rtc[0], acc.w);
        acc.x = fmaf(v1.x, rtc[1], acc.x);
        acc.y = fmaf(v1.y, rtc[1], acc.y);
        acc.z = fmaf(v1.z, rtc[1], acc.z);
        acc.w = fmaf(v1.w, rtc[1], acc.w);
        acc.x = fmaf(v2.x, rtc[2], acc.x);
        acc.y = fmaf(v2.y, rtc[2], acc.y);
        acc.z = fmaf(v2.z, rtc[2], acc.z);
        acc.w = fmaf(v2.w, rtc[2], acc.w);
        acc.x = fmaf(v3.x, rtc[3], acc.x);
        acc.y = fmaf(v3.y, rtc[3], acc.y);
        acc.z = fmaf(v3.z, rtc[3], acc.z);
        acc.w = fmaf(v3.w, rtc[3], acc.w);

        #pragma unroll
        for (int u = 0; u < U; ++u) { idc[u] = idn[u]; rtc[u] = rtn[u]; }
    }

    // tail: remaining quads of this wave, per-row guard
    for (int q = half + 2 * (U * iFull); 4 * q < n; q += 2) {
        int r = start + 4 * q + grp;
        if (r < end) {
            int   id = ids[r];
            float rt = ratings[r];
            const float4 v = ((const float4*)(table + (size_t)id * DIM))[col];
            acc.x = fmaf(v.x, rt, acc.x);
            acc.y = fmaf(v.y, rt, acc.y);
            acc.z = fmaf(v.z, rt, acc.z);
            acc.w = fmaf(v.w, rt, acc.w);
        }
    }

    // reduce the 4 row-groups within the wave (lanes xor 16, xor 32)
    #pragma unroll
    for (int m = 16; m <= 32; m <<= 1) {
        acc.x += __shfl_xor(acc.x, m);
        acc.y += __shfl_xor(acc.y, m);
        acc.z += __shfl_xor(acc.z, m);
        acc.w += __shfl_xor(acc.w, m);
    }

    // combine the two half-waves of this segment (fixed order: half0 + half1)
    if (half == 1 && grp == 0) part[seg_in_blk][col] = acc;
    __syncthreads();
    if (half == 0 && grp == 0) {
        float4 o = part[seg_in_blk][col];
        acc.x += o.x; acc.y += o.y; acc.z += o.z; acc.w += o.w;
        ((float4*)(out + (size_t)b * DIM))[col] = acc;
    }
}

extern "C" void kernel_launch(void* const* d_in, const int* in_sizes, int n_in,
                              void* d_out, int out_size, void* d_ws, size_t ws_size,
                              hipStream_t stream) {
    const int*   ids     = (const int*)  d_in[0];
    const float* ratings = (const float*)d_in[1];
    const int*   seg     = (const int*)  d_in[2];
    const float* table   = (const float*)d_in[3];
    float*       out     = (float*)      d_out;
    int*         offsets = (int*)        d_ws;   // (BATCH+1) ints

    seg_offsets_kernel<<<(TOTAL + 255) / 256, 256, 0, stream>>>(seg, offsets);
    embed_bag_kernel<<<BATCH / 2, 256, 0, stream>>>(ids, ratings, offsets, table, out);
}